// Round 5
// baseline (272.691 us; speedup 1.0000x reference)
//
#include <hip/hip_runtime.h>
#include <type_traits>

// Problem constants (ExaoneFlashAttention): B=4, S=1024, T=4096, D_MODEL=2048,
// H=32, KVH=8, HD=64, GROUPS=4, SCALE=1/8. All bf16 MFMA, f32 accum.
// Attention scale * log2(e) folded into Wq transpose -> softmax in exp2 domain.
// Max-free softmax (logits bounded). RoPE applied by rope_vkt pre-pass (in-place
// on qkv): QK^T is invariant under a common d-relabeling and rope commutes with
// the folded Q scale, so roping after the GEMM (on bf16) is exact up to one
// extra rounding. This frees the QKV GEMM to use BN=192 -> 256 blocks = 1/CU.

typedef __bf16 bf16x8 __attribute__((ext_vector_type(8)));
typedef __bf16 bf16x4 __attribute__((ext_vector_type(4)));
typedef float f32x4 __attribute__((ext_vector_type(4)));
typedef unsigned short u16;
typedef unsigned int u32;

#define DEVI __device__ __forceinline__

DEVI u16 f2bf(float f) {           // RNE f32->bf16 (finite inputs)
  u32 u = __builtin_bit_cast(u32, f);
  u += 0x7FFF + ((u >> 16) & 1);
  return (u16)(u >> 16);
}

// async global->LDS, 16B per lane. LDS dest must be wave-uniform base + lane*16.
DEVI void ld16_lds(const void* g, void* l) {
  __builtin_amdgcn_global_load_lds((const __attribute__((address_space(1))) u32*)g,
                                   (__attribute__((address_space(3))) u32*)l, 16, 0, 0);
}

template <int N> DEVI void waitvm() {   // counted vmcnt (T4) — compile-time immediate
  if constexpr (N == 0) asm volatile("s_waitcnt vmcnt(0)" ::: "memory");
  else if constexpr (N == 6) asm volatile("s_waitcnt vmcnt(6)" ::: "memory");
  else if constexpr (N == 7) asm volatile("s_waitcnt vmcnt(7)" ::: "memory");
  else static_assert(N == 0, "unsupported vmcnt");
}
DEVI void lgkm0() {                     // rule #18: sched_barrier after the wait
  asm volatile("s_waitcnt lgkmcnt(0)" ::: "memory");
  __builtin_amdgcn_sched_barrier(0);
}
DEVI void barrier() { __builtin_amdgcn_s_barrier(); }

// ---------------- elementwise f32 -> bf16 ----------------
__global__ __launch_bounds__(256) void convert_f32_bf16(const float* __restrict__ src,
                                                        u16* __restrict__ dst, int n4) {
  int i = blockIdx.x * 256 + threadIdx.x;
  if (i >= n4) return;
  float4 v = ((const float4*)src)[i];
  ushort4 o;
  o.x = f2bf(v.x); o.y = f2bf(v.y); o.z = f2bf(v.z); o.w = f2bf(v.w);
  ((ushort4*)dst)[i] = o;
}

// ---------------- transpose + convert + scale: src RxC f32 -> dst CxR bf16 ----------------
__global__ __launch_bounds__(256) void trans_f32_bf16(const float* __restrict__ src,
                                                      u16* __restrict__ dst, int R, int C,
                                                      float scale) {
  __shared__ float tile[32][33];
  int c0 = blockIdx.x * 32, r0 = blockIdx.y * 32;
  int tx = threadIdx.x & 31, ty = threadIdx.x >> 5;   // ty 0..7
#pragma unroll
  for (int i = 0; i < 32; i += 8)
    tile[ty + i][tx] = src[(size_t)(r0 + ty + i) * C + (c0 + tx)];
  __syncthreads();
#pragma unroll
  for (int i = 0; i < 32; i += 8)
    dst[(size_t)(c0 + ty + i) * R + (r0 + tx)] = f2bf(tile[tx][ty + i] * scale);
}

// ---------------- GEMM v5: 8-phase deep counted-vmcnt pipeline, pure GEMM --------------
// C(MxN) = A(MxK) * BT(NxK)^T, bf16 in, f32 acc. BM=256 x BN (192 QKV / 128 Wo),
// BK=64, 512 thr = 8 waves (2M x 4N), per-wave output 128 x (16*WN). Both grids are
// exactly 256 blocks = 1/CU (the round-4 QKV ran 192 blocks = 75% CUs). Double-
// buffered LDS. Stage stagger (verified lifetimes): B(buf) dead after P2, A(buf)
// dead after P3 -> tile T+2 issued entirely at P3 (B units) + P4 (A halves), tile
// T+3 at P7/P8. The counted wait at P4 (tile T+1, needed by P5) covers loads issued
// in the PREVIOUS iteration's P7/P8 -> ~4-5 phases of latency cover. VMW = one full
// K-tile in flight = 4 + WN loads/thread. vmcnt never drains to 0 in steady state.
// N-halves are asymmetric for WN=3: NH0=2 frags (phases P1/P4), NH1=1 frag (P2/P3).
// Chunk swizzle (T2): LDS[row][ch] holds global chunk ch^(row&7), staged via
// pre-swizzled global source (global_load_lds dest must be linear), read back with
// the same XOR -> conflict-free ds_read_b128 (0 conflicts measured).
// XCD swizzle (T1): nwg=256 %8==0, contiguous tile chunks per XCD.
template <typename OutT, int BN>
__global__ __launch_bounds__(512, 2) void gemm8(const u16* __restrict__ A,
                                                const u16* __restrict__ BT,
                                                OutT* __restrict__ C, int M, int N, int K) {
  constexpr int WN = BN / 64;          // n-frags per wave: 3 (QKV) or 2 (Wo)
  constexpr int NH0 = (WN + 1) / 2;    // frags in n-subhalf 0: 2 / 1
  constexpr int NH1 = WN - NH0;        // frags in n-subhalf 1: 1 / 1
  constexpr int VMW = 4 + WN;          // one K-tile in flight (A:4 + B:WN loads/thr)
  __shared__ u16 As[2][256 * 64];
  __shared__ u16 Bs[2][BN * 64];
  const int tid = threadIdx.x;
  const int lane = tid & 63, wave = tid >> 6;
  const int quad = lane >> 4, l16 = lane & 15;

  // ---- XCD-aware block swizzle (bijective: nwg % 8 == 0, both grids 256) ----
  const int nwg = gridDim.x * gridDim.y;
  const int bid = blockIdx.y * gridDim.x + blockIdx.x;
  const int swz = (bid & 7) * (nwg >> 3) + (bid >> 3);
  const int m0 = (swz / gridDim.x) * 256, n0 = (swz % gridDim.x) * BN;
  const int wr = wave >> 2, wc = wave & 3;   // 2M x 4N wave grid

  f32x4 acc[8][WN] = {};

  // ---- staging: 16B/lane linear dest, swizzled source ----
  auto stageA = [&](int t, int h) {          // A K-tile t, half h (128 rows), 2 loads/thr
    u16* D = &As[t & 1][h * 8192];
    const u16* G = A + (size_t)m0 * K + t * 64;
#pragma unroll
    for (int i = 0; i < 2; ++i) {
      int id = i * 512 + tid;
      int row = h * 128 + (id >> 3), ch = id & 7;
      ld16_lds(G + (size_t)row * K + (ch ^ (row & 7)) * 8, D + id * 8);
    }
  };
  auto stageB = [&](int t, int u) {          // B K-tile t, unit u (64 rows), 1 load/thr
    u16* D = &Bs[t & 1][u * 4096];
    const u16* G = BT + (size_t)n0 * K + t * 64;
    int row = u * 64 + (tid >> 3), ch = tid & 7;
    ld16_lds(G + (size_t)row * K + (ch ^ (row & 7)) * 8, D + tid * 8);
  };
  auto stageBall = [&](int t) {
#pragma unroll
    for (int u = 0; u < WN; ++u) stageB(t, u);
  };

  // ---- register fragment loads (swizzled ds_read_b128) ----
  bf16x8 af[4][2], bv0[NH0][2], bv1[NH1][2];
  auto ldA = [&](int msub, int d) {
#pragma unroll
    for (int i = 0; i < 4; ++i)
#pragma unroll
      for (int ks = 0; ks < 2; ++ks) {
        int r = wr * 128 + msub * 64 + i * 16 + l16;
        af[i][ks] = *(const bf16x8*)&As[d][r * 64 + (((ks * 4 + quad) ^ (r & 7)) * 8)];
      }
  };
  auto ldB0 = [&](int d) {
#pragma unroll
    for (int j = 0; j < NH0; ++j)
#pragma unroll
      for (int ks = 0; ks < 2; ++ks) {
        int rb = wc * (16 * WN) + j * 16 + l16;
        bv0[j][ks] = *(const bf16x8*)&Bs[d][rb * 64 + (((ks * 4 + quad) ^ (rb & 7)) * 8)];
      }
  };
  auto ldB1 = [&](int d) {
#pragma unroll
    for (int j = 0; j < NH1; ++j)
#pragma unroll
      for (int ks = 0; ks < 2; ++ks) {
        int rb = wc * (16 * WN) + (NH0 + j) * 16 + l16;
        bv1[j][ks] = *(const bf16x8*)&Bs[d][rb * 64 + (((ks * 4 + quad) ^ (rb & 7)) * 8)];
      }
  };
  auto mm0 = [&](int mo) {                   // quadrant on n-subhalf 0 (T5 wrap)
    __builtin_amdgcn_s_setprio(1);
#pragma unroll
    for (int i = 0; i < 4; ++i)
#pragma unroll
      for (int j = 0; j < NH0; ++j)
#pragma unroll
        for (int ks = 0; ks < 2; ++ks)
          acc[mo + i][j] =
              __builtin_amdgcn_mfma_f32_16x16x32_bf16(af[i][ks], bv0[j][ks], acc[mo + i][j], 0, 0, 0);
    __builtin_amdgcn_s_setprio(0);
  };
  auto mm1 = [&](int mo) {                   // quadrant on n-subhalf 1
    __builtin_amdgcn_s_setprio(1);
#pragma unroll
    for (int i = 0; i < 4; ++i)
#pragma unroll
      for (int j = 0; j < NH1; ++j)
#pragma unroll
        for (int ks = 0; ks < 2; ++ks)
          acc[mo + i][NH0 + j] =
              __builtin_amdgcn_mfma_f32_16x16x32_bf16(af[i][ks], bv1[j][ks], acc[mo + i][NH0 + j], 0, 0, 0);
    __builtin_amdgcn_s_setprio(0);
  };

  const int NT = K / 64;   // 32 (even) for both GEMMs

  // ---- prologue: tiles 0 AND 1 fully staged; wait tile0 (tile1's VMW stay flying)
  stageA(0, 0); stageA(0, 1); stageBall(0);
  stageA(1, 0); stageA(1, 1); stageBall(1);
  waitvm<VMW>();
  barrier();

#pragma unroll 1
  for (int T = 0; T < NT; T += 2) {
    const bool pf = (T + 2 < NT);   // NT even -> T+2 and T+3 prefetch coincide
    // ================ phases 1-4 : tile T in buf0 ================
    ldA(0, 0); ldB0(0);                  // P1 (no staging)
    barrier(); lgkm0();
    mm0(0);
    barrier();

    ldB1(0);                             // P2 (no staging)
    barrier(); lgkm0();
    mm1(0);
    barrier();

    ldA(1, 0);                           // P3: B(buf0) dead after P2
    if (pf) stageBall(T + 2);
    barrier(); lgkm0();
    mm1(4);
    barrier();

    if (pf) {                            // P4: A(buf0) dead after P3
      stageA(T + 2, 0); stageA(T + 2, 1);
      waitvm<VMW>();                     //   tile T+1 landed (issued prev P7/P8)
    } else {
      waitvm<0>();                       //   last iter: drain final tile
    }
    barrier();
    __builtin_amdgcn_sched_barrier(0);
    mm0(4);
    barrier();

    // ================ phases 5-8 : tile T+1 in buf1 ================
    ldA(0, 1); ldB0(1);                  // P5 (no staging)
    barrier(); lgkm0();
    mm0(0);
    barrier();

    ldB1(1);                             // P6 (no staging)
    barrier(); lgkm0();
    mm1(0);
    barrier();

    ldA(1, 1);                           // P7: B(buf1) dead after P6
    if (pf) stageBall(T + 3);
    barrier(); lgkm0();
    mm1(4);
    barrier();

    if (pf) {                            // P8: A(buf1) dead after P7
      stageA(T + 3, 0); stageA(T + 3, 1);
      waitvm<VMW>();                     //   tile T+2 landed (issued P3/P4)
      barrier();
      __builtin_amdgcn_sched_barrier(0);
      mm0(4);
      barrier();
    } else {
      mm0(4);                            // last iteration: no more LDS traffic
    }
  }

  // epilogue: C/D layout col=lane&15, row=quad*4+r
#pragma unroll
  for (int i = 0; i < 8; i++) {
    int row = m0 + wr * 128 + i * 16 + quad * 4;
#pragma unroll
    for (int j = 0; j < WN; j++) {
      int col = n0 + wc * (16 * WN) + j * 16 + l16;
#pragma unroll
      for (int r = 0; r < 4; r++) {
        size_t off = (size_t)(row + r) * N + col;
        if constexpr (sizeof(OutT) == 2) C[off] = f2bf(acc[i][j][r]);
        else C[off] = acc[i][j][r];
      }
    }
  }
}

// ---------------- rope_vkt: RoPE Q/K in-place + V tile images ---------------------------
// Grid (8 kt, 32 h, 4 b). Every block ropes the Q tile [128 tok x 64] of head h.
// Blocks with h<8 additionally rope the K tile of kvh=h and build the V image
// (transposed, chunk-swizzled, k-permuted) as before. RoPE pair (d, d+32) is
// in-row -> one thread owns a full pair group; cs/sn indexed by global token.
__global__ __launch_bounds__(256) void rope_vkt(u16* __restrict__ qkv,
                                                u16* __restrict__ vkt,
                                                const float* __restrict__ cs,
                                                const float* __restrict__ sn) {
  const int kt = blockIdx.x, h = blockIdx.y, b = blockIdx.z;
  const int tid = threadIdx.x;
  const size_t tok0 = (size_t)b * 1024 + (size_t)kt * 128;

  // ---- RoPE: 2 threads per row, 2 pair-groups (8 pairs each) per thread ----
  {
    const int r = tid >> 1, hf = tid & 1;
    const size_t t = tok0 + r;
    const float* cr = cs + t * 32;
    const float* sr = sn + t * 32;
    u16* qrow = qkv + t * 3072 + h * 64;
    u16* krow = qkv + t * 3072 + 2048 + h * 64;   // used only when h<8
#pragma unroll
    for (int gg = 0; gg < 2; ++gg) {
      const int g = hf * 2 + gg;                  // pair-group 0..3 (d = g*8+e)
      float cv[8], sv[8];
#pragma unroll
      for (int e = 0; e < 8; ++e) { cv[e] = cr[g * 8 + e]; sv[e] = sr[g * 8 + e]; }
      {
        bf16x8 a = *(bf16x8*)&qrow[g * 8];
        bf16x8 b2 = *(bf16x8*)&qrow[g * 8 + 32];
#pragma unroll
        for (int e = 0; e < 8; ++e) {
          float x1 = (float)a[e], x2 = (float)b2[e];
          a[e] = (__bf16)(x1 * cv[e] - x2 * sv[e]);
          b2[e] = (__bf16)(x2 * cv[e] + x1 * sv[e]);
        }
        *(bf16x8*)&qrow[g * 8] = a;
        *(bf16x8*)&qrow[g * 8 + 32] = b2;
      }
      if (h < 8) {
        bf16x8 a = *(bf16x8*)&krow[g * 8];
        bf16x8 b2 = *(bf16x8*)&krow[g * 8 + 32];
#pragma unroll
        for (int e = 0; e < 8; ++e) {
          float x1 = (float)a[e], x2 = (float)b2[e];
          a[e] = (__bf16)(x1 * cv[e] - x2 * sv[e]);
          b2[e] = (__bf16)(x2 * cv[e] + x1 * sv[e]);
        }
        *(bf16x8*)&krow[g * 8] = a;
        *(bf16x8*)&krow[g * 8 + 32] = b2;
      }
    }
  }
  if (h >= 8) return;

  // ---- V image build (kvh = h), unchanged from vkt_build ----
  __shared__ u16 Vn[128 * 64];
  const u16* src = qkv + tok0 * 3072 + 2560 + h * 64;
  {
    int tok = tid >> 1, hf = tid & 1;
    const uint4* s4 = (const uint4*)(src + (size_t)tok * 3072 + hf * 32);
    uint4* d4 = (uint4*)&Vn[tok * 64 + hf * 32];
#pragma unroll
    for (int j = 0; j < 4; j++) d4[j] = s4[j];
  }
  __syncthreads();
  u16* img = vkt + ((((size_t)b * 8 + h) * 8 + kt) << 13);   // 8192 u16 / image
#pragma unroll
  for (int i = 0; i < 4; i++) {
    int c = tid * 4 + i;                 // chunk index 0..1023
    int dd = c >> 4, chsw = c & 15;
    int ch = chsw ^ (dd & 15);
    u16 tmp[8];
#pragma unroll
    for (int p = 0; p < 8; p++) {
      int col = ch * 8 + p;
      int g = col >> 5, kl = col & 31;
      int kph = ((kl >> 2) & 1) * 16 + ((kl >> 4) & 1) * 8 + ((kl >> 3) & 1) * 4 + (kl & 3);
      tmp[p] = Vn[(g * 32 + kph) * 64 + dd];
    }
    *(uint4*)&img[c * 8] = *(const uint4*)tmp;
  }
}

// ---------------- flash attention v4 ----------------
// Grid (4, 32, 4) = 512 blocks = 2/CU. Two q-tiles per block (qtA=bx, qtB=7-bx):
// 9 tile-steps per block, K/V staged once for both. Transposed-score form,
// max-free exp2 softmax, P kept in registers via the k-permutation baked into
// the VkT images. K and VT double-buffered pure DMA. One barrier/iter.
// LDS: Ks 2x16KB + VT 2x16KB = 64KB -> 2 blocks/CU. T5 setprio on MFMA clusters.
__global__ __launch_bounds__(256, 2) void flash_attn(const u16* __restrict__ qkv,
                                                     const u16* __restrict__ vkt,
                                                     u16* __restrict__ attn) {
  __shared__ u16 Ks[2][128 * 64];
  __shared__ u16 VT[2][64 * 128];

  const int tid = threadIdx.x;
  const int lane = tid & 63, wave = tid >> 6;
  const int quad = lane >> 4, l16 = lane & 15;
  const int qtA = blockIdx.x, qtB = 7 - blockIdx.x;
  const int h = blockIdx.y, b = blockIdx.z, kvh = h >> 2;
  const size_t tokBase = (size_t)b * 1024;
  const int qcol = h * 64, kcol = 2048 + kvh * 64;
  const int srow = tid >> 3, spc = tid & 7, ssc = spc ^ (srow & 7);

  auto stageK = [&](const u16* gbase, u16* L) {   // natural 128x64, swizzled chunks
#pragma unroll
    for (int i = 0; i < 4; i++)
      ld16_lds(gbase + (size_t)(srow + i * 32) * 3072 + ssc * 8, &L[tid * 8 + i * 2048]);
  };
  const u16* vimg = vkt + (((size_t)b * 8 + kvh) << 16);
  auto stageV = [&](int kt, u16* L) {             // pre-swizzled image: linear copy
    const u16* g = vimg + ((size_t)kt << 13);
#pragma unroll
    for (int i = 0; i < 4; i++)
      ld16_lds(g + i * 2048 + tid * 8, &L[tid * 8 + i * 2048]);
  };

  // ---- stage both Q tiles into the K buffers, extract fragments ----
  stageK(qkv + (tokBase + qtA * 128) * 3072 + qcol, Ks[0]);
  stageK(qkv + (tokBase + qtB * 128) * 3072 + qcol, Ks[1]);
  __syncthreads();
  bf16x8 qfA[2][2], qfB[2][2];   // B-frag: n=q=l16, kdim=d contiguous
#pragma unroll
  for (int nq = 0; nq < 2; nq++) {
    int qrow = wave * 32 + nq * 16 + l16;
#pragma unroll
    for (int ks = 0; ks < 2; ks++) {
      int c = (ks * 4 + quad) ^ (qrow & 7);
      qfA[nq][ks] = *(const bf16x8*)&Ks[0][qrow * 64 + c * 8];
      qfB[nq][ks] = *(const bf16x8*)&Ks[1][qrow * 64 + c * 8];
    }
  }
  __syncthreads();   // Q reads done before K DMA overwrites

  float lA[2] = {0.f, 0.f}, lB[2] = {0.f, 0.f};
  f32x4 oA[4][2] = {}, oB[4][2] = {};   // O^T: d=md*16+quad*4+r, q=nq*16+l16

  auto proc = [&](const bf16x8 (&kf)[2][2], const bf16x8 (&va)[4], const bf16x8 (&qf)[2][2],
                  f32x4 (&o)[4][2], float (&lacc)[2], bool msk, int c) {
    f32x4 s[2][2] = {};   // [nq][mkl]: k = (c*2+mkl)*16 + quad*4 + r, q = nq*16+l16
    __builtin_amdgcn_s_setprio(1);
#pragma unroll
    for (int mkl = 0; mkl < 2; mkl++)
#pragma unroll
      for (int ks = 0; ks < 2; ks++) {
        s[0][mkl] = __builtin_amdgcn_mfma_f32_16x16x32_bf16(kf[mkl][ks], qf[0][ks], s[0][mkl], 0, 0, 0);
        s[1][mkl] = __builtin_amdgcn_mfma_f32_16x16x32_bf16(kf[mkl][ks], qf[1][ks], s[1][mkl], 0, 0, 0);
      }
    __builtin_amdgcn_s_setprio(0);
    if (msk) {
#pragma unroll
      for (int nq = 0; nq < 2; nq++) {
        int q = wave * 32 + nq * 16 + l16;
#pragma unroll
        for (int mkl = 0; mkl < 2; mkl++)
#pragma unroll
          for (int r = 0; r < 4; r++)
            if ((c * 2 + mkl) * 16 + quad * 4 + r > q) s[nq][mkl][r] = -3e38f;
      }
    }
    bf16x8 pf[2];
#pragma unroll
    for (int nq = 0; nq < 2; nq++) {
      float a0 = 0.f;
#pragma unroll
      for (int mkl = 0; mkl < 2; mkl++)
#pragma unroll
        for (int r = 0; r < 4; r++) {
          float p = __builtin_amdgcn_exp2f(s[nq][mkl][r]);
          s[nq][mkl][r] = p;
          a0 += p;
        }
      lacc[nq] += a0;
      pf[nq][0] = (__bf16)s[nq][0][0]; pf[nq][1] = (__bf16)s[nq][0][1];
      pf[nq][2] = (__bf16)s[nq][0][2]; pf[nq][3] = (__bf16)s[nq][0][3];
      pf[nq][4] = (__bf16)s[nq][1][0]; pf[nq][5] = (__bf16)s[nq][1][1];
      pf[nq][6] = (__bf16)s[nq][1][2]; pf[nq][7] = (__bf16)s[nq][1][3];
    }
    __builtin_amdgcn_s_setprio(1);
#pragma unroll
    for (int md = 0; md < 4; md++) {
      o[md][0] = __builtin_amdgcn_mfma_f32_16x16x32_bf16(va[md], pf[0], o[md][0], 0, 0, 0);
      o[md][1] = __builtin_amdgcn_mfma_f32_16x16x32_bf16(va[md], pf[1], o[md][1], 0, 0, 0);
    }
    __builtin_amdgcn_s_setprio(0);
  };

  // ---- main loop: double-buffered K + VT DMA, one barrier per iteration ----
  stageK(qkv + tokBase * 3072 + kcol, Ks[0]);
  stageV(0, VT[0]);

  for (int kt = 0; kt <= qtB; kt++) {
    const int cur = kt & 1;
    __syncthreads();   // drains DMA for kt; all waves done with bufs[1-cur]
    if (kt < qtB) {
      stageK(qkv + (tokBase + (kt + 1) * 128) * 3072 + kcol, Ks[1 - cur]);
      stageV(kt + 1, VT[1 - cur]);
    }
    const bool doA = (kt <= qtA), mA = (kt == qtA), mB = (kt == qtB);
    const u16* K = Ks[cur];
    const u16* V = VT[cur];
#pragma unroll
    for (int c = 0; c < 4; c++) {
      bf16x8 kf[2][2];   // A-frag: m=krow=mk*16+l16, kdim=d
#pragma unroll
      for (int mkl = 0; mkl < 2; mkl++) {
        int krow = (c * 2 + mkl) * 16 + l16;
#pragma unroll
        for (int ks = 0; ks < 2; ks++)
          kf[mkl][ks] = *(const bf16x8*)&K[krow * 64 + ((ks * 4 + quad) ^ (krow & 7)) * 8];
      }
      bf16x8 va[4];      // A-frag V^T: m=d=md*16+l16, k-chunk c
#pragma unroll
      for (int md = 0; md < 4; md++) {
        int dd = md * 16 + l16;
        va[md] = *(const bf16x8*)&V[dd * 128 + ((c * 4 + quad) ^ l16) * 8];
      }
      proc(kf, va, qfB, oB, lB, mB, c);
      if (doA) proc(kf, va, qfA, oA, lA, mA, c);
    }
  }

  // ---- epilogue: reduce l across quads (2 shfls), O/l, b64 stores ----
  auto epilogue = [&](const f32x4 (&o)[4][2], const float (&lacc)[2], int qt_tile) {
#pragma unroll
    for (int nq = 0; nq < 2; nq++) {
      float l = lacc[nq];
      l += __shfl_xor(l, 16);
      l += __shfl_xor(l, 32);
      float inv = 1.0f / l;
      int t = qt_tile * 128 + wave * 32 + nq * 16 + l16;
      size_t rowOff = (tokBase + t) * 2048 + qcol;
#pragma unroll
      for (int md = 0; md < 4; md++) {
        bf16x4 w;
        w[0] = (__bf16)(o[md][nq][0] * inv);
        w[1] = (__bf16)(o[md][nq][1] * inv);
        w[2] = (__bf16)(o[md][nq][2] * inv);
        w[3] = (__bf16)(o[md][nq][3] * inv);
        *(bf16x4*)&attn[rowOff + md * 16 + quad * 4] = w;
      }
    }
  };
  epilogue(oB, lB, qtB);
  epilogue(oA, lA, qtA);
}

// ---------------- launch ----------------
extern "C" void kernel_launch(void* const* d_in, const int* in_sizes, int n_in,
                              void* d_out, int out_size, void* d_ws, size_t ws_size,
                              hipStream_t stream) {
  const float* hs = (const float*)d_in[0];
  const float* cs = (const float*)d_in[1];
  const float* sn = (const float*)d_in[2];
  const float* Wq = (const float*)d_in[3];
  const float* Wk = (const float*)d_in[4];
  const float* Wv = (const float*)d_in[5];
  const float* Wo = (const float*)d_in[6];
  float* out = (float*)d_out;

  char* ws = (char*)d_ws;
  u16* hsB   = (u16*)(ws);                  // 4096x2048 bf16 (dead after qkv GEMM)
  u16* vkt   = (u16*)(ws);                  // 4MB VkT images, built after qkv GEMM
  u16* wqkvT = (u16*)(ws + 16777216);       // 3072x2048 bf16 [WqT;WkT;WvT]
  u16* woT   = (u16*)(ws + 29360128);       // 2048x2048 bf16
  u16* qkv   = (u16*)(ws + 37748736);       // 4096x3072 bf16
  u16* attnB = (u16*)(ws + 62914560);       // 4096x2048 bf16

  // attention scale folded into Wq: 1/8 * log2(e)  (rope commutes with the scale)
  const float QSCALE = 0.18033688011112042f;

  convert_f32_bf16<<<8192, 256, 0, stream>>>(hs, hsB, 4096 * 2048 / 4);
  trans_f32_bf16<<<dim3(64, 64), 256, 0, stream>>>(Wq, wqkvT, 2048, 2048, QSCALE);
  trans_f32_bf16<<<dim3(16, 64), 256, 0, stream>>>(Wk, wqkvT + (size_t)2048 * 2048, 2048, 512, 1.0f);
  trans_f32_bf16<<<dim3(16, 64), 256, 0, stream>>>(Wv, wqkvT + (size_t)2560 * 2048, 2048, 512, 1.0f);
  trans_f32_bf16<<<dim3(64, 64), 256, 0, stream>>>(Wo, woT, 2048, 2048, 1.0f);

  // QKV: 256x192 tile, 8-phase deep pipeline, grid 16x16 = 256 blocks = 1/CU.
  gemm8<u16, 192><<<dim3(16, 16), 512, 0, stream>>>(hsB, wqkvT, qkv, 4096, 3072, 2048);
  // RoPE Q+K in-place + V images.
  rope_vkt<<<dim3(8, 32, 4), 256, 0, stream>>>(qkv, vkt, cs, sn);
  flash_attn<<<dim3(4, 32, 4), 256, 0, stream>>>(qkv, vkt, attnB);
  // Wo: 256x128 tile, 8-phase, grid 16x16 = 256 blocks = 1/CU.
  gemm8<float, 128><<<dim3(16, 16), 512, 0, stream>>>(attnB, woT, out, 4096, 2048, 2048);
}

// Round 6
// 253.730 us; speedup vs baseline: 1.0747x; 1.0747x over previous
//
#include <hip/hip_runtime.h>
#include <type_traits>

// Problem constants (ExaoneFlashAttention): B=4, S=1024, T=4096, D_MODEL=2048,
// H=32, KVH=8, HD=64, GROUPS=4, SCALE=1/8. All bf16 MFMA, f32 accum.
// Attention scale * log2(e) folded into Wq transpose -> softmax in exp2 domain.
// Max-free softmax (logits bounded). RoPE applied by rope_vkt pre-pass (in-place
// on qkv; QK^T invariant under common d-relabeling, rope commutes with Q scale).

typedef __bf16 bf16x8 __attribute__((ext_vector_type(8)));
typedef __bf16 bf16x4 __attribute__((ext_vector_type(4)));
typedef float f32x4 __attribute__((ext_vector_type(4)));
typedef unsigned short u16;
typedef unsigned int u32;

#define DEVI __device__ __forceinline__

DEVI u16 f2bf(float f) {           // RNE f32->bf16 (finite inputs)
  u32 u = __builtin_bit_cast(u32, f);
  u += 0x7FFF + ((u >> 16) & 1);
  return (u16)(u >> 16);
}

// async global->LDS, 16B per lane. LDS dest must be wave-uniform base + lane*16.
DEVI void ld16_lds(const void* g, void* l) {
  __builtin_amdgcn_global_load_lds((const __attribute__((address_space(1))) u32*)g,
                                   (__attribute__((address_space(3))) u32*)l, 16, 0, 0);
}

template <int N> DEVI void waitvm() {   // counted vmcnt (T4) — compile-time immediate
  if constexpr (N == 0) asm volatile("s_waitcnt vmcnt(0)" ::: "memory");
  else if constexpr (N == 6) asm volatile("s_waitcnt vmcnt(6)" ::: "memory");
  else if constexpr (N == 7) asm volatile("s_waitcnt vmcnt(7)" ::: "memory");
  else if constexpr (N == 8) asm volatile("s_waitcnt vmcnt(8)" ::: "memory");
  else if constexpr (N == 10) asm volatile("s_waitcnt vmcnt(10)" ::: "memory");
  else static_assert(N == 0, "unsupported vmcnt");
}
DEVI void lgkm0() {                     // rule #18: sched_barrier after the wait
  asm volatile("s_waitcnt lgkmcnt(0)" ::: "memory");
  __builtin_amdgcn_sched_barrier(0);
}
DEVI void barrier() { __builtin_amdgcn_s_barrier(); }

// ---------------- fused prep: f32->bf16 convert + 4 weight transposes -------------------
// One dispatch replaces 5 (convert, Wq, Wk, Wv, Wo) — all mutually independent;
// saves ~4 inter-kernel gaps. Block ranges: [0,8192) convert; then trans blocks.
__global__ __launch_bounds__(256) void prep(const float* __restrict__ hs, u16* __restrict__ hsB,
                                            const float* __restrict__ Wq, const float* __restrict__ Wk,
                                            const float* __restrict__ Wv, const float* __restrict__ Wo,
                                            u16* __restrict__ wqkvT, u16* __restrict__ woT,
                                            float qscale) {
  int b = blockIdx.x;
  if (b < 8192) {                      // ---- convert hs (4096x2048 f32) -> hsB bf16 ----
    int i = b * 256 + threadIdx.x;
    float4 v = ((const float4*)hs)[i];
    ushort4 o;
    o.x = f2bf(v.x); o.y = f2bf(v.y); o.z = f2bf(v.z); o.w = f2bf(v.w);
    ((ushort4*)hsB)[i] = o;
    return;
  }
  b -= 8192;
  const float* src; u16* dst; int R, C, bx, by; float sc = 1.0f;
  if (b < 4096)      { src = Wq; dst = wqkvT;                         R = 2048; C = 2048; bx = b & 63; by = b >> 6; sc = qscale; }
  else if (b < 5120) { b -= 4096; src = Wk; dst = wqkvT + (size_t)2048 * 2048; R = 2048; C = 512; bx = b & 15; by = b >> 4; }
  else if (b < 6144) { b -= 5120; src = Wv; dst = wqkvT + (size_t)2560 * 2048; R = 2048; C = 512; bx = b & 15; by = b >> 4; }
  else               { b -= 6144; src = Wo; dst = woT;                R = 2048; C = 2048; bx = b & 63; by = b >> 6; }
  __shared__ float tile[32][33];
  int c0 = bx * 32, r0 = by * 32;
  int tx = threadIdx.x & 31, ty = threadIdx.x >> 5;   // ty 0..7
#pragma unroll
  for (int i = 0; i < 32; i += 8)
    tile[ty + i][tx] = src[(size_t)(r0 + ty + i) * C + (c0 + tx)];
  __syncthreads();
#pragma unroll
  for (int i = 0; i < 32; i += 8)
    dst[(size_t)(c0 + ty + i) * R + (r0 + tx)] = f2bf(tile[tx][ty + i] * sc);
}

// ---------------- GEMM v6: deep counted-vmcnt pipeline at 2 blocks/CU -------------------
// C(MxN) = A(MxK) * BT(NxK)^T, bf16 in, f32 acc. BM=128 x BN (192 QKV / 128 Wo),
// BK=64, 256 thr = 4 waves (2M x 2N). Wave output 64 x (BN/2), but its n-columns are
// the interleaved union {wc*SW..+SW} U {HW + wc*SW..+SW} so each B HALF ([0,HW) and
// [HW,BN)) is a contiguous, stageable row range read by exactly one phase.
// LDS = 2dbuf x (128 + BN) x 64 x 2B = 80 KB (QKV) / 64 KB (Wo) -> 2 blocks/CU:
// the round-5 1-block/CU lockstep serialized the CU's LDS-read and MFMA windows
// (measured 34.5% MfmaUtil); a second independent block overlaps them.
// 2 phases per K-tile t (buf = t&1):
//   P1: ds[ ldA(8) + ldB0(NH*2) ] ; stage B1(t+1)->buf^1 ; bar ; lgkm0 ;
//       mm0 (4xNHx2) ; waitvm<VMW> ; bar
//   P2: ds[ ldB1(NH*2) ]          ; stage A(t+2)+B0(t+2)->buf ; bar ; lgkm0 ;
//       mm1 (4xNHx2) ; waitvm<VMW> ; bar
// vmcnt ledger (issue order ... A+B0(t+1)@P2(t-1), B1(t+1)@P1(t), A+B0(t+2)@P2(t)):
//   P1(t)-end outstanding 13 -> wait<10> drains B1(t)   (needed by P2(t))   [2-phase flight]
//   P2(t)-end outstanding 17 -> wait<10> drains A+B0(t+1) (needed by P1(t+1)) [2-phase flight]
// Stage-vs-read safety: a region is staged only in a phase AFTER the closing barrier
// of its last reading phase (reads drain at that phase's lgkm0 < closing barrier).
// Tail (t+2>=NT): waitvm<0>. Chunk swizzle (T2) as before: LDS[row][ch]=global
// chunk ch^(row&7) via pre-swizzled source, same XOR on read -> conflict-free.
// XCD swizzle (T1): nwg=512 %8==0.
template <typename OutT, int BN>
__global__ __launch_bounds__(256, 2) void gemm2(const u16* __restrict__ A,
                                                const u16* __restrict__ BT,
                                                OutT* __restrict__ C, int M, int N, int K) {
  constexpr int NF = BN / 32;         // n-frags per wave: 6 (192) / 4 (128)
  constexpr int NH = NF / 2;          // frags per n-half: 3 / 2
  constexpr int HW = BN / 2;          // B half rows: 96 / 64
  constexpr int SW = HW / 2;          // per-wave span within a half: 48 / 32
  constexpr int LB0 = BN / 64;        // B-half stage loads/thr: 3 / 2
  constexpr int VMW = 4 + 2 * LB0;    // steady wait: 10 / 8
  constexpr int VMP = 4 + LB0;        // prologue wait: 7 / 6
  __shared__ u16 As[2][128 * 64];
  __shared__ u16 Bs[2][BN * 64];
  const int tid = threadIdx.x;
  const int lane = tid & 63, wave = tid >> 6;
  const int quad = lane >> 4, l16 = lane & 15;

  // ---- XCD-aware block swizzle (bijective: nwg = 512, %8 == 0) ----
  const int nwg = gridDim.x * gridDim.y;
  const int bid = blockIdx.y * gridDim.x + blockIdx.x;
  const int swz = (bid & 7) * (nwg >> 3) + (bid >> 3);
  const int m0 = (swz / gridDim.x) * 128, n0 = (swz % gridDim.x) * BN;
  const int wr = wave >> 1, wc = wave & 1;   // 2M x 2N wave grid

  f32x4 acc[4][NF] = {};

  // ---- staging: 16B/lane linear dest, pre-swizzled source ----
  auto stA = [&](int t) {                    // whole A tile (128 rows), 4 loads/thr
    u16* D = &As[t & 1][0];
    const u16* G = A + (size_t)m0 * K + t * 64;
#pragma unroll
    for (int i = 0; i < 4; ++i) {
      int id = i * 256 + tid, row = id >> 3, ch = id & 7;
      ld16_lds(G + (size_t)row * K + (ch ^ (row & 7)) * 8, D + id * 8);
    }
  };
  auto stB = [&](int t, int h) {             // B half h (HW rows), LB0 loads/thr
    u16* D = &Bs[t & 1][h * HW * 64];
    const u16* G = BT + (size_t)(n0 + h * HW) * K + t * 64;
#pragma unroll
    for (int i = 0; i < LB0; ++i) {
      int id = i * 256 + tid, row = id >> 3, ch = id & 7;
      // h*HW is a multiple of 8 -> (local row & 7) == (global row & 7): swizzle consistent
      ld16_lds(G + (size_t)row * K + (ch ^ (row & 7)) * 8, D + id * 8);
    }
  };

  // ---- register fragment loads (swizzled ds_read_b128) ----
  bf16x8 af[4][2], bv0[NH][2], bv1[NH][2];
  auto ldA = [&](int d) {
#pragma unroll
    for (int i = 0; i < 4; ++i)
#pragma unroll
      for (int ks = 0; ks < 2; ++ks) {
        int r = wr * 64 + i * 16 + l16;
        af[i][ks] = *(const bf16x8*)&As[d][r * 64 + (((ks * 4 + quad) ^ (r & 7)) * 8)];
      }
  };
  auto ldB = [&](bf16x8 (&bv)[NH][2], int half, int d) {
#pragma unroll
    for (int j = 0; j < NH; ++j)
#pragma unroll
      for (int ks = 0; ks < 2; ++ks) {
        int rb = half * HW + wc * SW + j * 16 + l16;
        bv[j][ks] = *(const bf16x8*)&Bs[d][rb * 64 + (((ks * 4 + quad) ^ (rb & 7)) * 8)];
      }
  };
  auto mm = [&](bf16x8 (&bv)[NH][2], int jo) {   // 4 x NH x 2 MFMA cluster (T5 wrap)
    __builtin_amdgcn_s_setprio(1);
#pragma unroll
    for (int i = 0; i < 4; ++i)
#pragma unroll
      for (int j = 0; j < NH; ++j)
#pragma unroll
        for (int ks = 0; ks < 2; ++ks)
          acc[i][jo + j] =
              __builtin_amdgcn_mfma_f32_16x16x32_bf16(af[i][ks], bv[j][ks], acc[i][jo + j], 0, 0, 0);
    __builtin_amdgcn_s_setprio(0);
  };

  const int NT = K / 64;   // 32 for both GEMMs

  // ---- prologue: tile0 full + A,B0 of tile1; drain tile0 (7/6 stay flying) ----
  stA(0); stB(0, 0); stB(0, 1);
  stA(1); stB(1, 0);
  waitvm<VMP>();
  barrier();

#pragma unroll 2
  for (int t = 0; t < NT; ++t) {
    const int buf = t & 1;
    const bool deep = (t + 2 < NT);
    // ---- P1 ----
    ldA(buf); ldB(bv0, 0, buf);
    if (t + 1 < NT) stB(t + 1, 1);           // B1(t+1) -> buf^1 (its rows last read
                                             //   at P2(t-1), closed by its barrier)
    barrier(); lgkm0();
    mm(bv0, 0);
    if (deep) waitvm<VMW>(); else waitvm<0>();   // drains B1(t) for P2(t)
    barrier();
    // ---- P2 ----
    ldB(bv1, 1, buf);
    if (deep) { stA(t + 2); stB(t + 2, 0); } // -> buf (A,B0 rows read in P1(t), closed)
    barrier(); lgkm0();
    mm(bv1, NH);
    if (deep) waitvm<VMW>(); else waitvm<0>();   // drains A+B0(t+1) for P1(t+1)
    barrier();
  }

  // ---- epilogue: C/D layout col=lane&15, row=quad*4+r ----
#pragma unroll
  for (int i = 0; i < 4; ++i) {
    int row = m0 + wr * 64 + i * 16 + quad * 4;
#pragma unroll
    for (int j = 0; j < NF; ++j) {
      int half = j / NH, jj = j % NH;
      int col = n0 + half * HW + wc * SW + jj * 16 + l16;
#pragma unroll
      for (int r = 0; r < 4; ++r) {
        size_t off = (size_t)(row + r) * N + col;
        if constexpr (sizeof(OutT) == 2) C[off] = f2bf(acc[i][j][r]);
        else C[off] = acc[i][j][r];
      }
    }
  }
}

// ---------------- rope_vkt: RoPE Q/K in-place + V tile images ---------------------------
// Grid (8 kt, 32 h, 4 b). Every block ropes the Q tile [128 tok x 64] of head h.
// Blocks with h<8 additionally rope the K tile of kvh=h and build the V image
// (transposed, chunk-swizzled, k-permuted). RoPE pair (d, d+32) is in-row ->
// one thread owns a full pair group; cs/sn indexed by global token.
__global__ __launch_bounds__(256) void rope_vkt(u16* __restrict__ qkv,
                                                u16* __restrict__ vkt,
                                                const float* __restrict__ cs,
                                                const float* __restrict__ sn) {
  const int kt = blockIdx.x, h = blockIdx.y, b = blockIdx.z;
  const int tid = threadIdx.x;
  const size_t tok0 = (size_t)b * 1024 + (size_t)kt * 128;

  // ---- RoPE: 2 threads per row, 2 pair-groups (8 pairs each) per thread ----
  {
    const int r = tid >> 1, hf = tid & 1;
    const size_t t = tok0 + r;
    const float* cr = cs + t * 32;
    const float* sr = sn + t * 32;
    u16* qrow = qkv + t * 3072 + h * 64;
    u16* krow = qkv + t * 3072 + 2048 + h * 64;   // used only when h<8
#pragma unroll
    for (int gg = 0; gg < 2; ++gg) {
      const int g = hf * 2 + gg;                  // pair-group 0..3 (d = g*8+e)
      float cv[8], sv[8];
#pragma unroll
      for (int e = 0; e < 8; ++e) { cv[e] = cr[g * 8 + e]; sv[e] = sr[g * 8 + e]; }
      {
        bf16x8 a = *(bf16x8*)&qrow[g * 8];
        bf16x8 b2 = *(bf16x8*)&qrow[g * 8 + 32];
#pragma unroll
        for (int e = 0; e < 8; ++e) {
          float x1 = (float)a[e], x2 = (float)b2[e];
          a[e] = (__bf16)(x1 * cv[e] - x2 * sv[e]);
          b2[e] = (__bf16)(x2 * cv[e] + x1 * sv[e]);
        }
        *(bf16x8*)&qrow[g * 8] = a;
        *(bf16x8*)&qrow[g * 8 + 32] = b2;
      }
      if (h < 8) {
        bf16x8 a = *(bf16x8*)&krow[g * 8];
        bf16x8 b2 = *(bf16x8*)&krow[g * 8 + 32];
#pragma unroll
        for (int e = 0; e < 8; ++e) {
          float x1 = (float)a[e], x2 = (float)b2[e];
          a[e] = (__bf16)(x1 * cv[e] - x2 * sv[e]);
          b2[e] = (__bf16)(x2 * cv[e] + x1 * sv[e]);
        }
        *(bf16x8*)&krow[g * 8] = a;
        *(bf16x8*)&krow[g * 8 + 32] = b2;
      }
    }
  }
  if (h >= 8) return;

  // ---- V image build (kvh = h) ----
  __shared__ u16 Vn[128 * 64];
  const u16* src = qkv + tok0 * 3072 + 2560 + h * 64;
  {
    int tok = tid >> 1, hf = tid & 1;
    const uint4* s4 = (const uint4*)(src + (size_t)tok * 3072 + hf * 32);
    uint4* d4 = (uint4*)&Vn[tok * 64 + hf * 32];
#pragma unroll
    for (int j = 0; j < 4; j++) d4[j] = s4[j];
  }
  __syncthreads();
  u16* img = vkt + ((((size_t)b * 8 + h) * 8 + kt) << 13);   // 8192 u16 / image
#pragma unroll
  for (int i = 0; i < 4; i++) {
    int c = tid * 4 + i;                 // chunk index 0..1023
    int dd = c >> 4, chsw = c & 15;
    int ch = chsw ^ (dd & 15);
    u16 tmp[8];
#pragma unroll
    for (int p = 0; p < 8; p++) {
      int col = ch * 8 + p;
      int g = col >> 5, kl = col & 31;
      int kph = ((kl >> 2) & 1) * 16 + ((kl >> 4) & 1) * 8 + ((kl >> 3) & 1) * 4 + (kl & 3);
      tmp[p] = Vn[(g * 32 + kph) * 64 + dd];
    }
    *(uint4*)&img[c * 8] = *(const uint4*)tmp;
  }
}

// ---------------- flash attention v4 ----------------
// Grid (4, 32, 4) = 512 blocks = 2/CU. Two q-tiles per block (qtA=bx, qtB=7-bx):
// 9 tile-steps per block, K/V staged once for both. Transposed-score form,
// max-free exp2 softmax, P kept in registers via the k-permutation baked into
// the VkT images. K and VT double-buffered pure DMA. One barrier/iter.
// LDS: Ks 2x16KB + VT 2x16KB = 64KB -> 2 blocks/CU. T5 setprio on MFMA clusters.
__global__ __launch_bounds__(256, 2) void flash_attn(const u16* __restrict__ qkv,
                                                     const u16* __restrict__ vkt,
                                                     u16* __restrict__ attn) {
  __shared__ u16 Ks[2][128 * 64];
  __shared__ u16 VT[2][64 * 128];

  const int tid = threadIdx.x;
  const int lane = tid & 63, wave = tid >> 6;
  const int quad = lane >> 4, l16 = lane & 15;
  const int qtA = blockIdx.x, qtB = 7 - blockIdx.x;
  const int h = blockIdx.y, b = blockIdx.z, kvh = h >> 2;
  const size_t tokBase = (size_t)b * 1024;
  const int qcol = h * 64, kcol = 2048 + kvh * 64;
  const int srow = tid >> 3, spc = tid & 7, ssc = spc ^ (srow & 7);

  auto stageK = [&](const u16* gbase, u16* L) {   // natural 128x64, swizzled chunks
#pragma unroll
    for (int i = 0; i < 4; i++)
      ld16_lds(gbase + (size_t)(srow + i * 32) * 3072 + ssc * 8, &L[tid * 8 + i * 2048]);
  };
  const u16* vimg = vkt + (((size_t)b * 8 + kvh) << 16);
  auto stageV = [&](int kt, u16* L) {             // pre-swizzled image: linear copy
    const u16* g = vimg + ((size_t)kt << 13);
#pragma unroll
    for (int i = 0; i < 4; i++)
      ld16_lds(g + i * 2048 + tid * 8, &L[tid * 8 + i * 2048]);
  };

  // ---- stage both Q tiles into the K buffers, extract fragments ----
  stageK(qkv + (tokBase + qtA * 128) * 3072 + qcol, Ks[0]);
  stageK(qkv + (tokBase + qtB * 128) * 3072 + qcol, Ks[1]);
  __syncthreads();
  bf16x8 qfA[2][2], qfB[2][2];   // B-frag: n=q=l16, kdim=d contiguous
#pragma unroll
  for (int nq = 0; nq < 2; nq++) {
    int qrow = wave * 32 + nq * 16 + l16;
#pragma unroll
    for (int ks = 0; ks < 2; ks++) {
      int c = (ks * 4 + quad) ^ (qrow & 7);
      qfA[nq][ks] = *(const bf16x8*)&Ks[0][qrow * 64 + c * 8];
      qfB[nq][ks] = *(const bf16x8*)&Ks[1][qrow * 64 + c * 8];
    }
  }
  __syncthreads();   // Q reads done before K DMA overwrites

  float lA[2] = {0.f, 0.f}, lB[2] = {0.f, 0.f};
  f32x4 oA[4][2] = {}, oB[4][2] = {};   // O^T: d=md*16+quad*4+r, q=nq*16+l16

  auto proc = [&](const bf16x8 (&kf)[2][2], const bf16x8 (&va)[4], const bf16x8 (&qf)[2][2],
                  f32x4 (&o)[4][2], float (&lacc)[2], bool msk, int c) {
    f32x4 s[2][2] = {};   // [nq][mkl]: k = (c*2+mkl)*16 + quad*4 + r, q = nq*16+l16
    __builtin_amdgcn_s_setprio(1);
#pragma unroll
    for (int mkl = 0; mkl < 2; mkl++)
#pragma unroll
      for (int ks = 0; ks < 2; ks++) {
        s[0][mkl] = __builtin_amdgcn_mfma_f32_16x16x32_bf16(kf[mkl][ks], qf[0][ks], s[0][mkl], 0, 0, 0);
        s[1][mkl] = __builtin_amdgcn_mfma_f32_16x16x32_bf16(kf[mkl][ks], qf[1][ks], s[1][mkl], 0, 0, 0);
      }
    __builtin_amdgcn_s_setprio(0);
    if (msk) {
#pragma unroll
      for (int nq = 0; nq < 2; nq++) {
        int q = wave * 32 + nq * 16 + l16;
#pragma unroll
        for (int mkl = 0; mkl < 2; mkl++)
#pragma unroll
          for (int r = 0; r < 4; r++)
            if ((c * 2 + mkl) * 16 + quad * 4 + r > q) s[nq][mkl][r] = -3e38f;
      }
    }
    bf16x8 pf[2];
#pragma unroll
    for (int nq = 0; nq < 2; nq++) {
      float a0 = 0.f;
#pragma unroll
      for (int mkl = 0; mkl < 2; mkl++)
#pragma unroll
        for (int r = 0; r < 4; r++) {
          float p = __builtin_amdgcn_exp2f(s[nq][mkl][r]);
          s[nq][mkl][r] = p;
          a0 += p;
        }
      lacc[nq] += a0;
      pf[nq][0] = (__bf16)s[nq][0][0]; pf[nq][1] = (__bf16)s[nq][0][1];
      pf[nq][2] = (__bf16)s[nq][0][2]; pf[nq][3] = (__bf16)s[nq][0][3];
      pf[nq][4] = (__bf16)s[nq][1][0]; pf[nq][5] = (__bf16)s[nq][1][1];
      pf[nq][6] = (__bf16)s[nq][1][2]; pf[nq][7] = (__bf16)s[nq][1][3];
    }
    __builtin_amdgcn_s_setprio(1);
#pragma unroll
    for (int md = 0; md < 4; md++) {
      o[md][0] = __builtin_amdgcn_mfma_f32_16x16x32_bf16(va[md], pf[0], o[md][0], 0, 0, 0);
      o[md][1] = __builtin_amdgcn_mfma_f32_16x16x32_bf16(va[md], pf[1], o[md][1], 0, 0, 0);
    }
    __builtin_amdgcn_s_setprio(0);
  };

  // ---- main loop: double-buffered K + VT DMA, one barrier per iteration ----
  stageK(qkv + tokBase * 3072 + kcol, Ks[0]);
  stageV(0, VT[0]);

  for (int kt = 0; kt <= qtB; kt++) {
    const int cur = kt & 1;
    __syncthreads();   // drains DMA for kt; all waves done with bufs[1-cur]
    if (kt < qtB) {
      stageK(qkv + (tokBase + (kt + 1) * 128) * 3072 + kcol, Ks[1 - cur]);
      stageV(kt + 1, VT[1 - cur]);
    }
    const bool doA = (kt <= qtA), mA = (kt == qtA), mB = (kt == qtB);
    const u16* K = Ks[cur];
    const u16* V = VT[cur];
#pragma unroll
    for (int c = 0; c < 4; c++) {
      bf16x8 kf[2][2];   // A-frag: m=krow=mk*16+l16, kdim=d
#pragma unroll
      for (int mkl = 0; mkl < 2; mkl++) {
        int krow = (c * 2 + mkl) * 16 + l16;
#pragma unroll
        for (int ks = 0; ks < 2; ks++)
          kf[mkl][ks] = *(const bf16x8*)&K[krow * 64 + ((ks * 4 + quad) ^ (krow & 7)) * 8];
      }
      bf16x8 va[4];      // A-frag V^T: m=d=md*16+l16, k-chunk c
#pragma unroll
      for (int md = 0; md < 4; md++) {
        int dd = md * 16 + l16;
        va[md] = *(const bf16x8*)&V[dd * 128 + ((c * 4 + quad) ^ l16) * 8];
      }
      proc(kf, va, qfB, oB, lB, mB, c);
      if (doA) proc(kf, va, qfA, oA, lA, mA, c);
    }
  }

  // ---- epilogue: reduce l across quads (2 shfls), O/l, b64 stores ----
  auto epilogue = [&](const f32x4 (&o)[4][2], const float (&lacc)[2], int qt_tile) {
#pragma unroll
    for (int nq = 0; nq < 2; nq++) {
      float l = lacc[nq];
      l += __shfl_xor(l, 16);
      l += __shfl_xor(l, 32);
      float inv = 1.0f / l;
      int t = qt_tile * 128 + wave * 32 + nq * 16 + l16;
      size_t rowOff = (tokBase + t) * 2048 + qcol;
#pragma unroll
      for (int md = 0; md < 4; md++) {
        bf16x4 w;
        w[0] = (__bf16)(o[md][nq][0] * inv);
        w[1] = (__bf16)(o[md][nq][1] * inv);
        w[2] = (__bf16)(o[md][nq][2] * inv);
        w[3] = (__bf16)(o[md][nq][3] * inv);
        *(bf16x4*)&attn[rowOff + md * 16 + quad * 4] = w;
      }
    }
  };
  epilogue(oB, lB, qtB);
  epilogue(oA, lA, qtA);
}

// ---------------- launch ----------------
extern "C" void kernel_launch(void* const* d_in, const int* in_sizes, int n_in,
                              void* d_out, int out_size, void* d_ws, size_t ws_size,
                              hipStream_t stream) {
  const float* hs = (const float*)d_in[0];
  const float* cs = (const float*)d_in[1];
  const float* sn = (const float*)d_in[2];
  const float* Wq = (const float*)d_in[3];
  const float* Wk = (const float*)d_in[4];
  const float* Wv = (const float*)d_in[5];
  const float* Wo = (const float*)d_in[6];
  float* out = (float*)d_out;

  char* ws = (char*)d_ws;
  u16* hsB   = (u16*)(ws);                  // 4096x2048 bf16 (dead after qkv GEMM)
  u16* vkt   = (u16*)(ws);                  // 4MB VkT images, built after qkv GEMM
  u16* wqkvT = (u16*)(ws + 16777216);       // 3072x2048 bf16 [WqT;WkT;WvT]
  u16* woT   = (u16*)(ws + 29360128);       // 2048x2048 bf16
  u16* qkv   = (u16*)(ws + 37748736);       // 4096x3072 bf16
  u16* attnB = (u16*)(ws + 62914560);       // 4096x2048 bf16

  // attention scale folded into Wq: 1/8 * log2(e)  (rope commutes with the scale)
  const float QSCALE = 0.18033688011112042f;

  // fused prep: convert (8192 blocks) + Wq (4096) + Wk (1024) + Wv (1024) + Wo (4096)
  prep<<<18432, 256, 0, stream>>>(hs, hsB, Wq, Wk, Wv, Wo, wqkvT, woT, QSCALE);

  // QKV: 128x192 tile, 2 blocks/CU deep pipeline, grid 16x32 = 512 = 2/CU.
  gemm2<u16, 192><<<dim3(16, 32), 256, 0, stream>>>(hsB, wqkvT, qkv, 4096, 3072, 2048);
  // RoPE Q+K in-place + V images.
  rope_vkt<<<dim3(8, 32, 4), 256, 0, stream>>>(qkv, vkt, cs, sn);
  flash_attn<<<dim3(4, 32, 4), 256, 0, stream>>>(qkv, vkt, attnB);
  // Wo: 128x128 tile, grid 16x32 = 512 = 2/CU.
  gemm2<float, 128><<<dim3(16, 32), 256, 0, stream>>>(attnB, woT, out, 4096, 2048, 2048);
}